// Round 5
// baseline (668.510 us; speedup 1.0000x reference)
//
#include <hip/hip_runtime.h>

#define CAP 64
#define DD 48

// ---------------- adjacency build (dst-bucketed, fixed capacity) ----------------
__global__ void build_adj_kernel(const int* __restrict__ ei, int E, int N,
                                 int* __restrict__ cnt, int* __restrict__ adj) {
    int e = blockIdx.x * blockDim.x + threadIdx.x;
    int Et = E + N;
    if (e >= Et) return;
    int s, d;
    if (e < E) { s = ei[e]; d = ei[E + e]; } else { s = e - E; d = e - E; }
    int pos = atomicAdd(&cnt[d], 1);
    if (pos < CAP) adj[d * CAP + pos] = s;
}

// ---------------- fp32 tiled GEMM + fused attention dots ----------------
// Hout[N,NCT] = X[N,K] @ W[K,NCT]; also asrc/adst[n,h] = sum_d Hout[n,h*48+d]*att[h][d].
// block tile 64x96, K-tile 32, 256 threads (16x16), thread tile 4x6.
template<int K, int NCT, int HEADS>
__global__ void gemm_kernel(const float* __restrict__ X, const float* __restrict__ W,
                            const float* __restrict__ att_s, const float* __restrict__ att_d,
                            float* __restrict__ Hout, float* __restrict__ asrc,
                            float* __restrict__ adst, int N) {
    __shared__ float XT[32][64];   // k-major x-tile (transposed)
    __shared__ float WS[32][96];
    int tid = threadIdx.x;
    int ty = tid >> 4, tx = tid & 15;
    int rb = blockIdx.x * 64;
    int c0 = blockIdx.y * 96;
    float acc[4][6];
#pragma unroll
    for (int i = 0; i < 4; i++)
#pragma unroll
        for (int j = 0; j < 6; j++) acc[i][j] = 0.f;

    for (int k0 = 0; k0 < K; k0 += 32) {
#pragma unroll
        for (int jj = 0; jj < 2; jj++) {
            int idx = tid + jj * 256;
            int r = idx >> 3, kq = idx & 7;
            int rg = rb + r;
            float4 v = make_float4(0.f, 0.f, 0.f, 0.f);
            if (rg < N) v = *reinterpret_cast<const float4*>(&X[(long)rg * K + k0 + kq * 4]);
            XT[kq * 4 + 0][r] = v.x; XT[kq * 4 + 1][r] = v.y;
            XT[kq * 4 + 2][r] = v.z; XT[kq * 4 + 3][r] = v.w;
        }
#pragma unroll
        for (int jj = 0; jj < 3; jj++) {
            int idx = tid + jj * 256;
            int kr = idx / 24, cq = idx % 24;
            float4 v = *reinterpret_cast<const float4*>(&W[(long)(k0 + kr) * NCT + c0 + cq * 4]);
            *reinterpret_cast<float4*>(&WS[kr][cq * 4]) = v;
        }
        __syncthreads();
#pragma unroll
        for (int kk = 0; kk < 32; kk++) {
            float a[4], b[6];
#pragma unroll
            for (int i = 0; i < 4; i++) a[i] = XT[kk][ty * 4 + i];
#pragma unroll
            for (int j = 0; j < 6; j++) b[j] = WS[kk][tx * 6 + j];
#pragma unroll
            for (int i = 0; i < 4; i++)
#pragma unroll
                for (int j = 0; j < 6; j++) acc[i][j] = fmaf(a[i], b[j], acc[i][j]);
        }
        __syncthreads();
    }
#pragma unroll
    for (int i = 0; i < 4; i++) {
        int r = rb + ty * 4 + i;
        if (r < N) {
#pragma unroll
            for (int j = 0; j < 6; j++)
                Hout[(long)r * NCT + c0 + tx * 6 + j] = acc[i][j];
        }
    }

    // ---- fused attention dots (head boundary at 48 = tx subgroup 0-7 / 8-15) ----
    int hl = tx >> 3;
    int head = (c0 / DD) + hl;
    int cih = tx * 6 - hl * DD;
    float ps[4] = {0.f, 0.f, 0.f, 0.f};
    float pd[4] = {0.f, 0.f, 0.f, 0.f};
#pragma unroll
    for (int j = 0; j < 6; j++) {
        float asv = att_s[head * DD + cih + j];
        float adv = att_d[head * DD + cih + j];
#pragma unroll
        for (int i = 0; i < 4; i++) {
            ps[i] = fmaf(acc[i][j], asv, ps[i]);
            pd[i] = fmaf(acc[i][j], adv, pd[i]);
        }
    }
#pragma unroll
    for (int i = 0; i < 4; i++) {
#pragma unroll
        for (int d = 1; d < 8; d <<= 1) {
            ps[i] += __shfl_xor(ps[i], d);
            pd[i] += __shfl_xor(pd[i], d);
        }
    }
    if ((tx & 7) == 0) {
#pragma unroll
        for (int i = 0; i < 4; i++) {
            int r = rb + ty * 4 + i;
            if (r < N) {
                asrc[r * HEADS + head] = ps[i];
                adst[r * HEADS + head] = pd[i];
            }
        }
    }
}

// ---------------- dst-centric fused softmax + aggregate + bias + relu ----------------
// R5: cnt+adj loads issued concurrently; gather loop is ALWAYS full 8-wide batches
// (wlds/slds zero beyond deg -> pad iterations contribute w=0*row0, L1-hit); VEC=3
// covers OUT=192 with all 64 lanes active.
template<int OUT, int HEADS, int VEC>
__global__ void agg_kernel(const float* __restrict__ Hin, const float* __restrict__ asrc,
                           const float* __restrict__ adst, const int* __restrict__ adj,
                           const int* __restrict__ cnt, const float* __restrict__ bias,
                           float* __restrict__ Oout, int N) {
    typedef float vec_t __attribute__((ext_vector_type(VEC)));
    constexpr int NL = OUT / VEC;            // active gather lanes
    __shared__ float wlds[4][HEADS][CAP];
    __shared__ float dlds[4][HEADS];
    __shared__ int   slds[4][CAP];
    int wv = threadIdx.x >> 6;
    int lane = threadIdx.x & 63;
    int n = blockIdx.x * 4 + wv;
    bool valid = (n < N);
    int nn = valid ? n : 0;
    // issue both loads concurrently (adj row is always in-bounds; mask after)
    int deg_raw = cnt[nn];
    int araw = adj[nn * CAP + lane];
    int deg = min(deg_raw, CAP);
    int s = (lane < deg) ? araw : 0;
    slds[wv][lane] = s;
    float w[HEADS];
#pragma unroll
    for (int h = 0; h < HEADS; h++) {
        float e = asrc[s * HEADS + h] + adst[nn * HEADS + h];
        e = (e < 0.f) ? 0.2f * e : e;               // leaky_relu, slope 0.2
        w[h] = (lane < deg) ? __expf(e) : 0.f;      // max-shift dropped: scale-invariant
        wlds[wv][h][lane] = w[h];
    }
#pragma unroll
    for (int h = 0; h < HEADS; h++) {               // den = wave-sum of weights
        float dsum = w[h];
#pragma unroll
        for (int off = 1; off < 64; off <<= 1) dsum += __shfl_xor(dsum, off);
        if (lane == 0) dlds[wv][h] = dsum;
    }
    __syncthreads();

    bool act = (lane < NL);
    int c = act ? lane * VEC : 0;                   // idle lanes alias lane0's line
    int head = c / DD;
    const float* wrow = wlds[wv][head];
    vec_t acc;
#pragma unroll
    for (int k = 0; k < VEC; k++) acc[k] = 0.f;

    for (int i = 0; i < deg; i += 8) {              // always full 8-wide batches
        int sv[8];
#pragma unroll
        for (int u = 0; u < 8; u++) sv[u] = slds[wv][i + u];
        vec_t hv[8];
#pragma unroll
        for (int u = 0; u < 8; u++)
            hv[u] = *reinterpret_cast<const vec_t*>(&Hin[(long)sv[u] * OUT + c]);
#pragma unroll
        for (int u = 0; u < 8; u++) {
            float ww = wrow[i + u];
#pragma unroll
            for (int k = 0; k < VEC; k++) acc[k] = fmaf(ww, hv[u][k], acc[k]);
        }
    }

    if (valid && act) {
        float invd = 1.f / (dlds[wv][head] + 1e-16f);
        vec_t o;
#pragma unroll
        for (int k = 0; k < VEC; k++) o[k] = fmaxf(fmaf(acc[k], invd, bias[c + k]), 0.f);
        *reinterpret_cast<vec_t*>(&Oout[(long)n * OUT + c]) = o;
    }
}

// ---------------- mean-pool: 128-thread groups, 64-node chunks, 4x-unrolled ----------------
__global__ void pool_kernel(const float* __restrict__ O, const int* __restrict__ batch,
                            float* __restrict__ sums, float* __restrict__ counts, int N) {
    int grp = threadIdx.x >> 7;                 // 4 groups of 128 per block
    int c = threadIdx.x & 127;                  // channel lane; active if < 96
    int n0 = (blockIdx.x * 4 + grp) * 64;
    if (n0 >= N) return;
    int nend = min(N, n0 + 64);
    bool act = (c < 96);
    float acc = 0.f; int cl = 0;
    int cur = batch[n0];
    int n = n0;
    for (; n + 4 <= nend; n += 4) {
        int g0 = batch[n], g1 = batch[n + 1], g2 = batch[n + 2], g3 = batch[n + 3];
        float v0 = 0.f, v1 = 0.f, v2 = 0.f, v3 = 0.f;
        if (act) {
            v0 = O[(long)n * 96 + c];       v1 = O[(long)(n + 1) * 96 + c];
            v2 = O[(long)(n + 2) * 96 + c]; v3 = O[(long)(n + 3) * 96 + c];
        }
#define POOL_STEP(g, v)                                                        \
        if ((g) != cur) {                                                      \
            if (act) atomicAdd(&sums[cur * 96 + c], acc);                      \
            if (c == 96) atomicAdd(&counts[cur], (float)cl);                   \
            acc = 0.f; cl = 0; cur = (g);                                      \
        }                                                                      \
        acc += (v); cl++;
        POOL_STEP(g0, v0) POOL_STEP(g1, v1) POOL_STEP(g2, v2) POOL_STEP(g3, v3)
    }
    for (; n < nend; n++) {
        int g = batch[n];
        float v = act ? O[(long)n * 96 + c] : 0.f;
        POOL_STEP(g, v)
    }
#undef POOL_STEP
    if (act) atomicAdd(&sums[cur * 96 + c], acc);
    if (c == 96) atomicAdd(&counts[cur], (float)cl);
}

// ---------------- FC head: one block per graph ----------------
__global__ void fc_kernel(const float* __restrict__ sums, const float* __restrict__ counts,
                          const float* __restrict__ W1, const float* __restrict__ b1,
                          const float* __restrict__ W2, const float* __restrict__ b2,
                          float* __restrict__ out) {
    __shared__ float p[96];
    __shared__ float h1[192];
    int g = blockIdx.x, tid = threadIdx.x;     // 192 threads
    if (tid < 96) p[tid] = sums[g * 96 + tid] / fmaxf(counts[g], 1.0f);
    __syncthreads();
    float s = b1[tid];
    for (int c = 0; c < 96; c++) s = fmaf(p[c], W1[c * 192 + tid], s);
    h1[tid] = fmaxf(s, 0.f);
    __syncthreads();
    if (tid < 96) {
        float s2 = b2[tid];
        for (int j = 0; j < 192; j++) s2 = fmaf(h1[j], W2[j * 96 + tid], s2);
        out[g * 96 + tid] = s2;
    }
}

extern "C" void kernel_launch(void* const* d_in, const int* in_sizes, int n_in,
                              void* d_out, int out_size, void* d_ws, size_t ws_size,
                              hipStream_t stream) {
    const float* x     = (const float*)d_in[0];
    const int*   ei    = (const int*)d_in[1];
    const int*   batch = (const int*)d_in[2];
    const float* W0  = (const float*)d_in[3];
    const float* as0 = (const float*)d_in[4];
    const float* ad0 = (const float*)d_in[5];
    const float* b0  = (const float*)d_in[6];
    const float* W1  = (const float*)d_in[7];
    const float* as1 = (const float*)d_in[8];
    const float* ad1 = (const float*)d_in[9];
    const float* b1  = (const float*)d_in[10];
    const float* W2  = (const float*)d_in[11];
    const float* as2 = (const float*)d_in[12];
    const float* ad2 = (const float*)d_in[13];
    const float* b2  = (const float*)d_in[14];
    const float* fcW1 = (const float*)d_in[15];
    const float* fcb1 = (const float*)d_in[16];
    const float* fcW2 = (const float*)d_in[17];
    const float* fcb2 = (const float*)d_in[18];

    const int N = in_sizes[0] / 128;
    const int E = in_sizes[1] / 2;

    char* ws = (char*)d_ws;
    float* Hbuf = (float*)ws;                                   // N*192 f
    float* Obuf = (float*)(ws + (size_t)N * 192 * 4);           // N*192 f
    float* ASRC = (float*)(ws + (size_t)N * 384 * 4);           // N*4 f
    float* ADST = ASRC + (size_t)N * 4;                         // N*4 f
    int*   ADJ  = (int*)(ADST + (size_t)N * 4);                 // N*CAP i
    int*   CNT  = ADJ + (size_t)N * CAP;                        // N i
    float* SUMS = (float*)(CNT + N);                            // 64*96 f
    float* COUNTS = SUMS + 64 * 96;                             // 64 f

    hipMemsetAsync(CNT, 0, ((size_t)N + 64 * 96 + 64) * 4, stream);

    int Et = E + N;
    build_adj_kernel<<<(Et + 255) / 256, 256, 0, stream>>>(ei, E, N, CNT, ADJ);

    int rb = (N + 63) / 64;

    // layer 0: 128 -> 4x48
    gemm_kernel<128, 192, 4><<<dim3(rb, 2), 256, 0, stream>>>(x, W0, as0, ad0, Hbuf, ASRC, ADST, N);
    agg_kernel<192, 4, 3><<<(N + 3) / 4, 256, 0, stream>>>(Hbuf, ASRC, ADST, ADJ, CNT, b0, Obuf, N);

    // layer 1: 192 -> 2x48
    gemm_kernel<192, 96, 2><<<dim3(rb, 1), 256, 0, stream>>>(Obuf, W1, as1, ad1, Hbuf, ASRC, ADST, N);
    agg_kernel<96, 2, 2><<<(N + 3) / 4, 256, 0, stream>>>(Hbuf, ASRC, ADST, ADJ, CNT, b1, Obuf, N);

    // layer 2: 96 -> 2x48
    gemm_kernel<96, 96, 2><<<dim3(rb, 1), 256, 0, stream>>>(Obuf, W2, as2, ad2, Hbuf, ASRC, ADST, N);
    agg_kernel<96, 2, 2><<<(N + 3) / 4, 256, 0, stream>>>(Hbuf, ASRC, ADST, ADJ, CNT, b2, Obuf, N);

    // pooling + FC head
    pool_kernel<<<(N / 256) + 1, 512, 0, stream>>>(Obuf, batch, SUMS, COUNTS, N);
    fc_kernel<<<64, 192, 0, stream>>>(SUMS, COUNTS, fcW1, fcb1, fcW2, fcb2, (float*)d_out);
}

// Round 6
// 585.129 us; speedup vs baseline: 1.1425x; 1.1425x over previous
//
#include <hip/hip_runtime.h>

#define CAP 64
#define DD 48

__device__ __forceinline__ unsigned int bf16r(float f) {   // round-to-nearest-even bf16
    unsigned int u = __float_as_uint(f);
    return (u + 0x7FFFu + ((u >> 16) & 1u)) >> 16;
}

// ---------------- adjacency build (dst-bucketed, fixed capacity) ----------------
__global__ void build_adj_kernel(const int* __restrict__ ei, int E, int N,
                                 int* __restrict__ cnt, int* __restrict__ adj) {
    int e = blockIdx.x * blockDim.x + threadIdx.x;
    int Et = E + N;
    if (e >= Et) return;
    int s, d;
    if (e < E) { s = ei[e]; d = ei[E + e]; } else { s = e - E; d = e - E; }
    int pos = atomicAdd(&cnt[d], 1);
    if (pos < CAP) adj[d * CAP + pos] = s;
}

// ---------------- fp32 tiled GEMM -> bf16 H + fused attention dots ----------------
// Computes h = X@W in fp32 registers; writes H as BF16 (gather payload) and
// asrc/adst in fp32. No fp32 H is materialized (nothing else consumes it).
template<int K, int NCT, int HEADS>
__global__ void gemm_kernel(const float* __restrict__ X, const float* __restrict__ W,
                            const float* __restrict__ att_s, const float* __restrict__ att_d,
                            unsigned int* __restrict__ Hb,      // bf16 pairs, N*NCT/2 uints
                            float* __restrict__ asrc, float* __restrict__ adst, int N) {
    __shared__ float XT[32][64];   // k-major x-tile (transposed)
    __shared__ float WS[32][96];
    int tid = threadIdx.x;
    int ty = tid >> 4, tx = tid & 15;
    int rb = blockIdx.x * 64;
    int c0 = blockIdx.y * 96;
    float acc[4][6];
#pragma unroll
    for (int i = 0; i < 4; i++)
#pragma unroll
        for (int j = 0; j < 6; j++) acc[i][j] = 0.f;

    for (int k0 = 0; k0 < K; k0 += 32) {
#pragma unroll
        for (int jj = 0; jj < 2; jj++) {
            int idx = tid + jj * 256;
            int r = idx >> 3, kq = idx & 7;
            int rg = rb + r;
            float4 v = make_float4(0.f, 0.f, 0.f, 0.f);
            if (rg < N) v = *reinterpret_cast<const float4*>(&X[(long)rg * K + k0 + kq * 4]);
            XT[kq * 4 + 0][r] = v.x; XT[kq * 4 + 1][r] = v.y;
            XT[kq * 4 + 2][r] = v.z; XT[kq * 4 + 3][r] = v.w;
        }
#pragma unroll
        for (int jj = 0; jj < 3; jj++) {
            int idx = tid + jj * 256;
            int kr = idx / 24, cq = idx % 24;
            float4 v = *reinterpret_cast<const float4*>(&W[(long)(k0 + kr) * NCT + c0 + cq * 4]);
            *reinterpret_cast<float4*>(&WS[kr][cq * 4]) = v;
        }
        __syncthreads();
#pragma unroll
        for (int kk = 0; kk < 32; kk++) {
            float a[4], b[6];
#pragma unroll
            for (int i = 0; i < 4; i++) a[i] = XT[kk][ty * 4 + i];
#pragma unroll
            for (int j = 0; j < 6; j++) b[j] = WS[kk][tx * 6 + j];
#pragma unroll
            for (int i = 0; i < 4; i++)
#pragma unroll
                for (int j = 0; j < 6; j++) acc[i][j] = fmaf(a[i], b[j], acc[i][j]);
        }
        __syncthreads();
    }
    // ---- bf16 H store: 3 packed uints per row-chunk (cols c0+tx*6 .. +5) ----
#pragma unroll
    for (int i = 0; i < 4; i++) {
        int r = rb + ty * 4 + i;
        if (r < N) {
            unsigned int* p = &Hb[((long)r * NCT + c0 + tx * 6) >> 1];
#pragma unroll
            for (int q = 0; q < 3; q++)
                p[q] = bf16r(acc[i][2 * q]) | (bf16r(acc[i][2 * q + 1]) << 16);
        }
    }

    // ---- fused attention dots (head boundary at 48 = tx subgroup 0-7 / 8-15) ----
    int hl = tx >> 3;
    int head = (c0 / DD) + hl;
    int cih = tx * 6 - hl * DD;
    float ps[4] = {0.f, 0.f, 0.f, 0.f};
    float pd[4] = {0.f, 0.f, 0.f, 0.f};
#pragma unroll
    for (int j = 0; j < 6; j++) {
        float asv = att_s[head * DD + cih + j];
        float adv = att_d[head * DD + cih + j];
#pragma unroll
        for (int i = 0; i < 4; i++) {
            ps[i] = fmaf(acc[i][j], asv, ps[i]);
            pd[i] = fmaf(acc[i][j], adv, pd[i]);
        }
    }
#pragma unroll
    for (int i = 0; i < 4; i++) {
#pragma unroll
        for (int d = 1; d < 8; d <<= 1) {
            ps[i] += __shfl_xor(ps[i], d);
            pd[i] += __shfl_xor(pd[i], d);
        }
    }
    if ((tx & 7) == 0) {
#pragma unroll
        for (int i = 0; i < 4; i++) {
            int r = rb + ty * 4 + i;
            if (r < N) {
                asrc[r * HEADS + head] = ps[i];
                adst[r * HEADS + head] = pd[i];
            }
        }
    }
}

// ---------------- dst-centric fused softmax + aggregate + bias + relu ----------------
// R6: H gathered as BF16 (halved fabric bytes). Lane owns PAIRS consecutive bf16
// pairs (PAIRS*2 channels); 48 active lanes. Softmax weights fp32 via LDS broadcast,
// denominator = wave reduction; loop always full 8-wide batches (pads hit row 0).
template<int OUT, int HEADS, int PAIRS>
__global__ void agg_kernel(const unsigned int* __restrict__ Hb,
                           const float* __restrict__ asrc, const float* __restrict__ adst,
                           const int* __restrict__ adj, const int* __restrict__ cnt,
                           const float* __restrict__ bias, float* __restrict__ Oout, int N) {
    typedef unsigned int pk_t __attribute__((ext_vector_type(PAIRS)));
    constexpr int NL = OUT / (2 * PAIRS);      // active gather lanes (48)
    __shared__ float wlds[4][HEADS][CAP];
    __shared__ float dlds[4][HEADS];
    __shared__ int   slds[4][CAP];
    int wv = threadIdx.x >> 6;
    int lane = threadIdx.x & 63;
    int n = blockIdx.x * 4 + wv;
    bool valid = (n < N);
    int nn = valid ? n : 0;
    int deg_raw = cnt[nn];                     // issue cnt+adj concurrently
    int araw = adj[nn * CAP + lane];
    int deg = min(deg_raw, CAP);
    int s = (lane < deg) ? araw : 0;
    slds[wv][lane] = s;
    float w[HEADS];
#pragma unroll
    for (int h = 0; h < HEADS; h++) {
        float e = asrc[s * HEADS + h] + adst[nn * HEADS + h];
        e = (e < 0.f) ? 0.2f * e : e;               // leaky_relu, slope 0.2
        w[h] = (lane < deg) ? __expf(e) : 0.f;      // max-shift dropped: scale-invariant
        wlds[wv][h][lane] = w[h];
    }
#pragma unroll
    for (int h = 0; h < HEADS; h++) {               // den = wave-sum of weights
        float dsum = w[h];
#pragma unroll
        for (int off = 1; off < 64; off <<= 1) dsum += __shfl_xor(dsum, off);
        if (lane == 0) dlds[wv][h] = dsum;
    }
    __syncthreads();

    bool act = (lane < NL);
    int c = act ? lane * 2 * PAIRS : 0;             // 2*PAIRS channels per lane
    int head = c / DD;                              // no head-straddle (48 % (2*PAIRS) == 0)
    const float* wrow = wlds[wv][head];
    float acc[2 * PAIRS];
#pragma unroll
    for (int k = 0; k < 2 * PAIRS; k++) acc[k] = 0.f;

    for (int i = 0; i < deg; i += 8) {              // always full 8-wide batches
        int sv[8];
#pragma unroll
        for (int u = 0; u < 8; u++) sv[u] = slds[wv][i + u];
        pk_t hv[8];
#pragma unroll
        for (int u = 0; u < 8; u++)
            hv[u] = *reinterpret_cast<const pk_t*>(&Hb[((long)sv[u] * OUT + c) >> 1]);
#pragma unroll
        for (int u = 0; u < 8; u++) {
            float ww = wrow[i + u];
#pragma unroll
            for (int q = 0; q < PAIRS; q++) {
                float lo = __uint_as_float(hv[u][q] << 16);
                float hi = __uint_as_float(hv[u][q] & 0xFFFF0000u);
                acc[2 * q]     = fmaf(ww, lo, acc[2 * q]);
                acc[2 * q + 1] = fmaf(ww, hi, acc[2 * q + 1]);
            }
        }
    }

    if (valid && act) {
        float invd = 1.f / (dlds[wv][head] + 1e-16f);
        float o[2 * PAIRS];
#pragma unroll
        for (int k = 0; k < 2 * PAIRS; k++)
            o[k] = fmaxf(fmaf(acc[k], invd, bias[c + k]), 0.f);
#pragma unroll
        for (int q = 0; q < PAIRS; q++)
            *reinterpret_cast<float2*>(&Oout[(long)n * OUT + c + 2 * q]) =
                make_float2(o[2 * q], o[2 * q + 1]);
    }
}

// ---------------- mean-pool: 128-thread groups, 64-node chunks, 4x-unrolled ----------------
__global__ void pool_kernel(const float* __restrict__ O, const int* __restrict__ batch,
                            float* __restrict__ sums, float* __restrict__ counts, int N) {
    int grp = threadIdx.x >> 7;                 // 4 groups of 128 per block
    int c = threadIdx.x & 127;                  // channel lane; active if < 96
    int n0 = (blockIdx.x * 4 + grp) * 64;
    if (n0 >= N) return;
    int nend = min(N, n0 + 64);
    bool act = (c < 96);
    float acc = 0.f; int cl = 0;
    int cur = batch[n0];
    int n = n0;
    for (; n + 4 <= nend; n += 4) {
        int g0 = batch[n], g1 = batch[n + 1], g2 = batch[n + 2], g3 = batch[n + 3];
        float v0 = 0.f, v1 = 0.f, v2 = 0.f, v3 = 0.f;
        if (act) {
            v0 = O[(long)n * 96 + c];       v1 = O[(long)(n + 1) * 96 + c];
            v2 = O[(long)(n + 2) * 96 + c]; v3 = O[(long)(n + 3) * 96 + c];
        }
#define POOL_STEP(g, v)                                                        \
        if ((g) != cur) {                                                      \
            if (act) atomicAdd(&sums[cur * 96 + c], acc);                      \
            if (c == 96) atomicAdd(&counts[cur], (float)cl);                   \
            acc = 0.f; cl = 0; cur = (g);                                      \
        }                                                                      \
        acc += (v); cl++;
        POOL_STEP(g0, v0) POOL_STEP(g1, v1) POOL_STEP(g2, v2) POOL_STEP(g3, v3)
    }
    for (; n < nend; n++) {
        int g = batch[n];
        float v = act ? O[(long)n * 96 + c] : 0.f;
        POOL_STEP(g, v)
    }
#undef POOL_STEP
    if (act) atomicAdd(&sums[cur * 96 + c], acc);
    if (c == 96) atomicAdd(&counts[cur], (float)cl);
}

// ---------------- FC head: one block per graph ----------------
__global__ void fc_kernel(const float* __restrict__ sums, const float* __restrict__ counts,
                          const float* __restrict__ W1, const float* __restrict__ b1,
                          const float* __restrict__ W2, const float* __restrict__ b2,
                          float* __restrict__ out) {
    __shared__ float p[96];
    __shared__ float h1[192];
    int g = blockIdx.x, tid = threadIdx.x;     // 192 threads
    if (tid < 96) p[tid] = sums[g * 96 + tid] / fmaxf(counts[g], 1.0f);
    __syncthreads();
    float s = b1[tid];
    for (int c = 0; c < 96; c++) s = fmaf(p[c], W1[c * 192 + tid], s);
    h1[tid] = fmaxf(s, 0.f);
    __syncthreads();
    if (tid < 96) {
        float s2 = b2[tid];
        for (int j = 0; j < 192; j++) s2 = fmaf(h1[j], W2[j * 96 + tid], s2);
        out[g * 96 + tid] = s2;
    }
}

extern "C" void kernel_launch(void* const* d_in, const int* in_sizes, int n_in,
                              void* d_out, int out_size, void* d_ws, size_t ws_size,
                              hipStream_t stream) {
    const float* x     = (const float*)d_in[0];
    const int*   ei    = (const int*)d_in[1];
    const int*   batch = (const int*)d_in[2];
    const float* W0  = (const float*)d_in[3];
    const float* as0 = (const float*)d_in[4];
    const float* ad0 = (const float*)d_in[5];
    const float* b0  = (const float*)d_in[6];
    const float* W1  = (const float*)d_in[7];
    const float* as1 = (const float*)d_in[8];
    const float* ad1 = (const float*)d_in[9];
    const float* b1  = (const float*)d_in[10];
    const float* W2  = (const float*)d_in[11];
    const float* as2 = (const float*)d_in[12];
    const float* ad2 = (const float*)d_in[13];
    const float* b2  = (const float*)d_in[14];
    const float* fcW1 = (const float*)d_in[15];
    const float* fcb1 = (const float*)d_in[16];
    const float* fcW2 = (const float*)d_in[17];
    const float* fcb2 = (const float*)d_in[18];

    const int N = in_sizes[0] / 128;
    const int E = in_sizes[1] / 2;

    char* ws = (char*)d_ws;
    unsigned int* Hb = (unsigned int*)ws;                       // N*192 bf16 = N*96 uints
    float* Obuf = (float*)(ws + (size_t)N * 96 * 4);            // N*192 f
    float* ASRC = (float*)(ws + (size_t)N * (96 + 192) * 4);    // N*4 f
    float* ADST = ASRC + (size_t)N * 4;                         // N*4 f
    int*   ADJ  = (int*)(ADST + (size_t)N * 4);                 // N*CAP i
    int*   CNT  = ADJ + (size_t)N * CAP;                        // N i
    float* SUMS = (float*)(CNT + N);                            // 64*96 f
    float* COUNTS = SUMS + 64 * 96;                             // 64 f

    hipMemsetAsync(CNT, 0, ((size_t)N + 64 * 96 + 64) * 4, stream);

    int Et = E + N;
    build_adj_kernel<<<(Et + 255) / 256, 256, 0, stream>>>(ei, E, N, CNT, ADJ);

    int rb = (N + 63) / 64;

    // layer 0: 128 -> 4x48   (PAIRS=2: lane owns 4 channels, 48 lanes, dwordx2 gather)
    gemm_kernel<128, 192, 4><<<dim3(rb, 2), 256, 0, stream>>>(x, W0, as0, ad0, Hb, ASRC, ADST, N);
    agg_kernel<192, 4, 2><<<(N + 3) / 4, 256, 0, stream>>>(Hb, ASRC, ADST, ADJ, CNT, b0, Obuf, N);

    // layer 1: 192 -> 2x48   (PAIRS=1: lane owns 2 channels, 48 lanes, dword gather)
    gemm_kernel<192, 96, 2><<<dim3(rb, 1), 256, 0, stream>>>(Obuf, W1, as1, ad1, Hb, ASRC, ADST, N);
    agg_kernel<96, 2, 1><<<(N + 3) / 4, 256, 0, stream>>>(Hb, ASRC, ADST, ADJ, CNT, b1, Obuf, N);

    // layer 2: 96 -> 2x48
    gemm_kernel<96, 96, 2><<<dim3(rb, 1), 256, 0, stream>>>(Obuf, W2, as2, ad2, Hb, ASRC, ADST, N);
    agg_kernel<96, 2, 1><<<(N + 3) / 4, 256, 0, stream>>>(Hb, ASRC, ADST, ADJ, CNT, b2, Obuf, N);

    // pooling + FC head
    pool_kernel<<<(N / 256) + 1, 512, 0, stream>>>(Obuf, batch, SUMS, COUNTS, N);
    fc_kernel<<<64, 192, 0, stream>>>(SUMS, COUNTS, fcW1, fcb1, fcW2, fcb2, (float*)d_out);
}

// Round 7
// 498.840 us; speedup vs baseline: 1.3401x; 1.1730x over previous
//
#include <hip/hip_runtime.h>

#define CAP 64
#define DD 48

typedef short v8s __attribute__((ext_vector_type(8)));
typedef float v4f __attribute__((ext_vector_type(4)));

__device__ __forceinline__ unsigned int bf16r(float f) {   // round-to-nearest-even bf16
    unsigned int u = __float_as_uint(f);
    return (u + 0x7FFFu + ((u >> 16) & 1u)) >> 16;
}

__device__ __forceinline__ v8s ld_frag(const ushort* p) {  // p 8B-aligned in LDS
    const uint2* q = reinterpret_cast<const uint2*>(p);
    uint2 a = q[0], b = q[1];
    union { unsigned int u[4]; v8s v; } t;
    t.u[0] = a.x; t.u[1] = a.y; t.u[2] = b.x; t.u[3] = b.y;
    return t.v;
}

// ---------------- adjacency build (dst-bucketed, fixed capacity) ----------------
__global__ void build_adj_kernel(const int* __restrict__ ei, int E, int N,
                                 int* __restrict__ cnt, int* __restrict__ adj) {
    int e = blockIdx.x * blockDim.x + threadIdx.x;
    int Et = E + N;
    if (e >= Et) return;
    int s, d;
    if (e < E) { s = ei[e]; d = ei[E + e]; } else { s = e - E; d = e - E; }
    int pos = atomicAdd(&cnt[d], 1);
    if (pos < CAP) adj[d * CAP + pos] = s;
}

// ---------------- fp32 -> bf16 casts ----------------
__global__ void cast_x_kernel(const float* __restrict__ x, unsigned int* __restrict__ xb, long n2) {
    long i = (long)blockIdx.x * blockDim.x + threadIdx.x;
    if (i >= n2) return;
    float2 v = reinterpret_cast<const float2*>(x)[i];
    xb[i] = bf16r(v.x) | (bf16r(v.y) << 16);
}

// W [K][NC] fp32 -> WT [NC][K] bf16 (transposed: B-frag wants contiguous k per column)
__global__ void convw_kernel(const float* __restrict__ W, ushort* __restrict__ WT, int K, int NC) {
    int i = blockIdx.x * blockDim.x + threadIdx.x;
    if (i >= K * NC) return;
    int k = i / NC, n = i % NC;
    WT[n * K + k] = (ushort)bf16r(W[i]);
}

// ---------------- bf16 MFMA GEMM + fused attention dots ----------------
// H[N,NCT] = X[N,K] @ W[K,NCT] via mfma_f32_16x16x32_bf16.
// Block: 128 rows x 96 cols, 4 waves (wave w: rows w*32..+31, 2x6 16x16 C-frags).
// LDS row stride 40 ushorts: all b64 accesses, <=2-way bank aliasing (free).
// Layouts (HW-verified): A/B [m|n=lane&15][k=quad*8+j]; C/D col=lane&15,row=quad*4+reg.
template<int K, int NCT, int HEADS>
__global__ void gemm_mfma(const ushort* __restrict__ Xb, const ushort* __restrict__ WT,
                          const float* __restrict__ att_s, const float* __restrict__ att_d,
                          ushort* __restrict__ Hb, float* __restrict__ asrc,
                          float* __restrict__ adst, int N) {
    __shared__ ushort XT_l[128 * 40];
    __shared__ ushort WT_l[96 * 40];
    int tid = threadIdx.x;
    int wv = tid >> 6, lane = tid & 63;
    int m = lane & 15, quad = lane >> 4;
    int rb = blockIdx.x * 128;
    int c0 = blockIdx.y * 96;
    int mw = wv * 32;
    v4f acc[2][6];
#pragma unroll
    for (int mi = 0; mi < 2; mi++)
#pragma unroll
        for (int nb = 0; nb < 6; nb++) acc[mi][nb] = (v4f){0.f, 0.f, 0.f, 0.f};

    for (int k0 = 0; k0 < K; k0 += 32) {
        // stage X-tile 128x32 bf16 (chunks of 8 elems; b128 global, 2x b64 LDS)
#pragma unroll
        for (int t = 0; t < 2; t++) {
            int ch = tid + t * 256;
            int r = ch >> 2, kq = ch & 3;
            int rg = rb + r;
            uint4 v = make_uint4(0u, 0u, 0u, 0u);
            if (rg < N) v = *reinterpret_cast<const uint4*>(&Xb[(long)rg * K + k0 + kq * 8]);
            uint2* d = reinterpret_cast<uint2*>(&XT_l[r * 40 + kq * 8]);
            d[0] = make_uint2(v.x, v.y);
            d[1] = make_uint2(v.z, v.w);
        }
        // stage W-tile 96x32 bf16 (from pre-transposed WT[NCT][K])
#pragma unroll
        for (int t = 0; t < 2; t++) {
            int ch = tid + t * 256;
            if (ch < 384) {
                int wr = ch >> 2, kq = ch & 3;
                uint4 v = *reinterpret_cast<const uint4*>(&WT[(long)(c0 + wr) * K + k0 + kq * 8]);
                uint2* d = reinterpret_cast<uint2*>(&WT_l[wr * 40 + kq * 8]);
                d[0] = make_uint2(v.x, v.y);
                d[1] = make_uint2(v.z, v.w);
            }
        }
        __syncthreads();
        v8s af[2], bf[6];
        af[0] = ld_frag(&XT_l[(mw + m) * 40 + quad * 8]);
        af[1] = ld_frag(&XT_l[(mw + 16 + m) * 40 + quad * 8]);
#pragma unroll
        for (int nb = 0; nb < 6; nb++)
            bf[nb] = ld_frag(&WT_l[(nb * 16 + m) * 40 + quad * 8]);
#pragma unroll
        for (int mi = 0; mi < 2; mi++)
#pragma unroll
            for (int nb = 0; nb < 6; nb++)
                acc[mi][nb] = __builtin_amdgcn_mfma_f32_16x16x32_bf16(af[mi], bf[nb], acc[mi][nb], 0, 0, 0);
        __syncthreads();
    }

    // ---- bf16 H store (C-frag: row = mw+mi*16+quad*4+r, col = c0+nb*16+m) ----
#pragma unroll
    for (int mi = 0; mi < 2; mi++)
#pragma unroll
        for (int r = 0; r < 4; r++) {
            int R = rb + mw + mi * 16 + quad * 4 + r;
            if (R < N) {
#pragma unroll
                for (int nb = 0; nb < 6; nb++)
                    Hb[(long)R * NCT + c0 + nb * 16 + m] = (ushort)bf16r(acc[mi][nb][r]);
            }
        }

    // ---- fused attention dots from fp32 accumulator ----
    float aS[6], aD[6];
    int h0 = c0 / DD;                         // c0=0 -> heads 0,1; c0=96 -> heads 2,3
#pragma unroll
    for (int nb = 0; nb < 6; nb++) {
        int cb = nb * 16 + m;
        int hl = cb / DD;
        int cih = cb - hl * DD;
        aS[nb] = att_s[(h0 + hl) * DD + cih];
        aD[nb] = att_d[(h0 + hl) * DD + cih];
    }
#pragma unroll
    for (int mi = 0; mi < 2; mi++)
#pragma unroll
        for (int r = 0; r < 4; r++) {
            float ps0 = 0.f, ps1 = 0.f, pd0 = 0.f, pd1 = 0.f;
#pragma unroll
            for (int nb = 0; nb < 3; nb++) {
                ps0 = fmaf(acc[mi][nb][r], aS[nb], ps0);
                pd0 = fmaf(acc[mi][nb][r], aD[nb], pd0);
            }
#pragma unroll
            for (int nb = 3; nb < 6; nb++) {
                ps1 = fmaf(acc[mi][nb][r], aS[nb], ps1);
                pd1 = fmaf(acc[mi][nb][r], aD[nb], pd1);
            }
#pragma unroll
            for (int d = 1; d < 16; d <<= 1) {     // reduce over 16 cols (same quad)
                ps0 += __shfl_xor(ps0, d); ps1 += __shfl_xor(ps1, d);
                pd0 += __shfl_xor(pd0, d); pd1 += __shfl_xor(pd1, d);
            }
            int R = rb + mw + mi * 16 + quad * 4 + r;
            if (m == 0 && R < N) {
                asrc[R * HEADS + h0]     = ps0;
                asrc[R * HEADS + h0 + 1] = ps1;
                adst[R * HEADS + h0]     = pd0;
                adst[R * HEADS + h0 + 1] = pd1;
            }
        }
}

// ---------------- dst-centric fused softmax + aggregate + bias + relu ----------------
// bf16 H gather; OBF16 selects bf16 (next-layer GEMM input) vs fp32 (pool) output.
template<int OUT, int HEADS, int PAIRS, bool OBF16>
__global__ void agg_kernel(const unsigned int* __restrict__ Hb,
                           const float* __restrict__ asrc, const float* __restrict__ adst,
                           const int* __restrict__ adj, const int* __restrict__ cnt,
                           const float* __restrict__ bias,
                           unsigned int* __restrict__ Ob, float* __restrict__ Of, int N) {
    typedef unsigned int pk_t __attribute__((ext_vector_type(PAIRS)));
    constexpr int NL = OUT / (2 * PAIRS);      // active gather lanes (48)
    __shared__ float wlds[4][HEADS][CAP];
    __shared__ float dlds[4][HEADS];
    __shared__ int   slds[4][CAP];
    int wv = threadIdx.x >> 6;
    int lane = threadIdx.x & 63;
    int n = blockIdx.x * 4 + wv;
    bool valid = (n < N);
    int nn = valid ? n : 0;
    int deg_raw = cnt[nn];                     // issue cnt+adj concurrently
    int araw = adj[nn * CAP + lane];
    int deg = min(deg_raw, CAP);
    int s = (lane < deg) ? araw : 0;
    slds[wv][lane] = s;
    float w[HEADS];
#pragma unroll
    for (int h = 0; h < HEADS; h++) {
        float e = asrc[s * HEADS + h] + adst[nn * HEADS + h];
        e = (e < 0.f) ? 0.2f * e : e;               // leaky_relu, slope 0.2
        w[h] = (lane < deg) ? __expf(e) : 0.f;      // max-shift dropped: scale-invariant
        wlds[wv][h][lane] = w[h];
    }
#pragma unroll
    for (int h = 0; h < HEADS; h++) {               // den = wave-sum of weights
        float dsum = w[h];
#pragma unroll
        for (int off = 1; off < 64; off <<= 1) dsum += __shfl_xor(dsum, off);
        if (lane == 0) dlds[wv][h] = dsum;
    }
    __syncthreads();

    bool act = (lane < NL);
    int c = act ? lane * 2 * PAIRS : 0;
    int head = c / DD;
    const float* wrow = wlds[wv][head];
    float acc[2 * PAIRS];
#pragma unroll
    for (int k = 0; k < 2 * PAIRS; k++) acc[k] = 0.f;

    for (int i = 0; i < deg; i += 8) {              // always full 8-wide batches
        int sv[8];
#pragma unroll
        for (int u = 0; u < 8; u++) sv[u] = slds[wv][i + u];
        pk_t hv[8];
#pragma unroll
        for (int u = 0; u < 8; u++)
            hv[u] = *reinterpret_cast<const pk_t*>(&Hb[((long)sv[u] * OUT + c) >> 1]);
#pragma unroll
        for (int u = 0; u < 8; u++) {
            float ww = wrow[i + u];
#pragma unroll
            for (int q = 0; q < PAIRS; q++) {
                float lo = __uint_as_float(hv[u][q] << 16);
                float hi = __uint_as_float(hv[u][q] & 0xFFFF0000u);
                acc[2 * q]     = fmaf(ww, lo, acc[2 * q]);
                acc[2 * q + 1] = fmaf(ww, hi, acc[2 * q + 1]);
            }
        }
    }

    if (valid && act) {
        float invd = 1.f / (dlds[wv][head] + 1e-16f);
        float o[2 * PAIRS];
#pragma unroll
        for (int k = 0; k < 2 * PAIRS; k++)
            o[k] = fmaxf(fmaf(acc[k], invd, bias[c + k]), 0.f);
        if (OBF16) {
            pk_t pk;
#pragma unroll
            for (int q = 0; q < PAIRS; q++)
                pk[q] = bf16r(o[2 * q]) | (bf16r(o[2 * q + 1]) << 16);
            *reinterpret_cast<pk_t*>(&Ob[((long)n * OUT + c) >> 1]) = pk;
        } else {
#pragma unroll
            for (int q = 0; q < PAIRS; q++)
                *reinterpret_cast<float2*>(&Of[(long)n * OUT + c + 2 * q]) =
                    make_float2(o[2 * q], o[2 * q + 1]);
        }
    }
}

// ---------------- mean-pool: 128-thread groups, 64-node chunks, 4x-unrolled ----------------
__global__ void pool_kernel(const float* __restrict__ O, const int* __restrict__ batch,
                            float* __restrict__ sums, float* __restrict__ counts, int N) {
    int grp = threadIdx.x >> 7;                 // 4 groups of 128 per block
    int c = threadIdx.x & 127;                  // channel lane; active if < 96
    int n0 = (blockIdx.x * 4 + grp) * 64;
    if (n0 >= N) return;
    int nend = min(N, n0 + 64);
    bool act = (c < 96);
    float acc = 0.f; int cl = 0;
    int cur = batch[n0];
    int n = n0;
    for (; n + 4 <= nend; n += 4) {
        int g0 = batch[n], g1 = batch[n + 1], g2 = batch[n + 2], g3 = batch[n + 3];
        float v0 = 0.f, v1 = 0.f, v2 = 0.f, v3 = 0.f;
        if (act) {
            v0 = O[(long)n * 96 + c];       v1 = O[(long)(n + 1) * 96 + c];
            v2 = O[(long)(n + 2) * 96 + c]; v3 = O[(long)(n + 3) * 96 + c];
        }
#define POOL_STEP(g, v)                                                        \
        if ((g) != cur) {                                                      \
            if (act) atomicAdd(&sums[cur * 96 + c], acc);                      \
            if (c == 96) atomicAdd(&counts[cur], (float)cl);                   \
            acc = 0.f; cl = 0; cur = (g);                                      \
        }                                                                      \
        acc += (v); cl++;
        POOL_STEP(g0, v0) POOL_STEP(g1, v1) POOL_STEP(g2, v2) POOL_STEP(g3, v3)
    }
    for (; n < nend; n++) {
        int g = batch[n];
        float v = act ? O[(long)n * 96 + c] : 0.f;
        POOL_STEP(g, v)
    }
#undef POOL_STEP
    if (act) atomicAdd(&sums[cur * 96 + c], acc);
    if (c == 96) atomicAdd(&counts[cur], (float)cl);
}

// ---------------- FC head: one block per graph ----------------
__global__ void fc_kernel(const float* __restrict__ sums, const float* __restrict__ counts,
                          const float* __restrict__ W1, const float* __restrict__ b1,
                          const float* __restrict__ W2, const float* __restrict__ b2,
                          float* __restrict__ out) {
    __shared__ float p[96];
    __shared__ float h1[192];
    int g = blockIdx.x, tid = threadIdx.x;     // 192 threads
    if (tid < 96) p[tid] = sums[g * 96 + tid] / fmaxf(counts[g], 1.0f);
    __syncthreads();
    float s = b1[tid];
    for (int c = 0; c < 96; c++) s = fmaf(p[c], W1[c * 192 + tid], s);
    h1[tid] = fmaxf(s, 0.f);
    __syncthreads();
    if (tid < 96) {
        float s2 = b2[tid];
        for (int j = 0; j < 192; j++) s2 = fmaf(h1[j], W2[j * 96 + tid], s2);
        out[g * 96 + tid] = s2;
    }
}

extern "C" void kernel_launch(void* const* d_in, const int* in_sizes, int n_in,
                              void* d_out, int out_size, void* d_ws, size_t ws_size,
                              hipStream_t stream) {
    const float* x     = (const float*)d_in[0];
    const int*   ei    = (const int*)d_in[1];
    const int*   batch = (const int*)d_in[2];
    const float* W0  = (const float*)d_in[3];
    const float* as0 = (const float*)d_in[4];
    const float* ad0 = (const float*)d_in[5];
    const float* b0  = (const float*)d_in[6];
    const float* W1  = (const float*)d_in[7];
    const float* as1 = (const float*)d_in[8];
    const float* ad1 = (const float*)d_in[9];
    const float* b1  = (const float*)d_in[10];
    const float* W2  = (const float*)d_in[11];
    const float* as2 = (const float*)d_in[12];
    const float* ad2 = (const float*)d_in[13];
    const float* b2  = (const float*)d_in[14];
    const float* fcW1 = (const float*)d_in[15];
    const float* fcb1 = (const float*)d_in[16];
    const float* fcW2 = (const float*)d_in[17];
    const float* fcb2 = (const float*)d_in[18];

    const int N = in_sizes[0] / 128;
    const int E = in_sizes[1] / 2;

    char* ws = (char*)d_ws;
    unsigned int* Xb   = (unsigned int*)ws;                          // N*128 bf16 = N*256 B
    unsigned int* Hb   = (unsigned int*)(ws + (size_t)N * 256);      // N*192 bf16 = N*384 B
    unsigned int* Ob   = (unsigned int*)(ws + (size_t)N * 640);      // N*192 bf16 = N*384 B
    float*        Obuf = (float*)(ws + (size_t)N * 1024);            // N*96 f32  = N*384 B
    float*        ASRC = (float*)(ws + (size_t)N * 1408);            // N*4 f
    float*        ADST = (float*)(ws + (size_t)N * 1424);            // N*4 f
    int*          ADJ  = (int*)(ws + (size_t)N * 1440);              // N*CAP i  = N*256 B
    int*          CNT  = (int*)(ws + (size_t)N * 1696);              // N i
    float*        SUMS = (float*)(ws + (size_t)N * 1700);            // 64*96 f
    float*        COUNTS = SUMS + 64 * 96;                           // 64 f
    ushort*       WT0  = (ushort*)(COUNTS + 64);                     // 192*128 bf16
    ushort*       WT1  = WT0 + 192 * 128;                            // 96*192 bf16
    ushort*       WT2  = WT1 + 96 * 192;                             // 96*96 bf16

    // zero: CNT + SUMS + COUNTS (contiguous)
    hipMemsetAsync(CNT, 0, (size_t)N * 4 + (64 * 96 + 64) * 4, stream);

    int Et = E + N;
    build_adj_kernel<<<(Et + 255) / 256, 256, 0, stream>>>(ei, E, N, CNT, ADJ);

    long n2 = (long)N * 64;
    cast_x_kernel<<<(int)((n2 + 255) / 256), 256, 0, stream>>>(x, Xb, n2);
    convw_kernel<<<(128 * 192 + 255) / 256, 256, 0, stream>>>(W0, WT0, 128, 192);
    convw_kernel<<<(192 * 96 + 255) / 256, 256, 0, stream>>>(W1, WT1, 192, 96);
    convw_kernel<<<(96 * 96 + 255) / 256, 256, 0, stream>>>(W2, WT2, 96, 96);

    int gb = (N + 127) / 128;

    // layer 0: 128 -> 4x48
    gemm_mfma<128, 192, 4><<<dim3(gb, 2), 256, 0, stream>>>((const ushort*)Xb, WT0, as0, ad0,
                                                            (ushort*)Hb, ASRC, ADST, N);
    agg_kernel<192, 4, 2, true><<<(N + 3) / 4, 256, 0, stream>>>(Hb, ASRC, ADST, ADJ, CNT, b0, Ob, nullptr, N);

    // layer 1: 192 -> 2x48
    gemm_mfma<192, 96, 2><<<dim3(gb, 1), 256, 0, stream>>>((const ushort*)Ob, WT1, as1, ad1,
                                                           (ushort*)Hb, ASRC, ADST, N);
    agg_kernel<96, 2, 1, true><<<(N + 3) / 4, 256, 0, stream>>>(Hb, ASRC, ADST, ADJ, CNT, b1, Ob, nullptr, N);

    // layer 2: 96 -> 2x48
    gemm_mfma<96, 96, 2><<<dim3(gb, 1), 256, 0, stream>>>((const ushort*)Ob, WT2, as2, ad2,
                                                          (ushort*)Hb, ASRC, ADST, N);
    agg_kernel<96, 2, 1, false><<<(N + 3) / 4, 256, 0, stream>>>(Hb, ASRC, ADST, ADJ, CNT, b2, nullptr, Obuf, N);

    // pooling + FC head
    pool_kernel<<<(N / 256) + 1, 512, 0, stream>>>(Obuf, batch, SUMS, COUNTS, N);
    fc_kernel<<<64, 192, 0, stream>>>(SUMS, COUNTS, fcW1, fcb1, fcW2, fcb2, (float*)d_out);
}

// Round 8
// 493.659 us; speedup vs baseline: 1.3542x; 1.0105x over previous
//
#include <hip/hip_runtime.h>

#define CAP 64
#define DD 48

typedef short v8s __attribute__((ext_vector_type(8)));
typedef float v4f __attribute__((ext_vector_type(4)));
typedef float v2f __attribute__((ext_vector_type(2)));

__device__ __forceinline__ unsigned int bf16r(float f) {   // round-to-nearest-even bf16
    unsigned int u = __float_as_uint(f);
    return (u + 0x7FFFu + ((u >> 16) & 1u)) >> 16;
}

__device__ __forceinline__ v8s ld_frag(const ushort* p) {  // p 8B-aligned in LDS
    const uint2* q = reinterpret_cast<const uint2*>(p);
    uint2 a = q[0], b = q[1];
    union { unsigned int u[4]; v8s v; } t;
    t.u[0] = a.x; t.u[1] = a.y; t.u[2] = b.x; t.u[3] = b.y;
    return t.v;
}

// ---------------- adjacency build (dst-bucketed, fixed capacity) ----------------
__global__ void build_adj_kernel(const int* __restrict__ ei, int E, int N,
                                 int* __restrict__ cnt, int* __restrict__ adj) {
    int e = blockIdx.x * blockDim.x + threadIdx.x;
    int Et = E + N;
    if (e >= Et) return;
    int s, d;
    if (e < E) { s = ei[e]; d = ei[E + e]; } else { s = e - E; d = e - E; }
    int pos = atomicAdd(&cnt[d], 1);
    if (pos < CAP) adj[d * CAP + pos] = s;
}

// ---------------- fp32 -> bf16 casts ----------------
__global__ void cast_x_kernel(const float* __restrict__ x, unsigned int* __restrict__ xb, long n2) {
    long i = (long)blockIdx.x * blockDim.x + threadIdx.x;
    if (i >= n2) return;
    float2 v = reinterpret_cast<const float2*>(x)[i];
    xb[i] = bf16r(v.x) | (bf16r(v.y) << 16);
}

// W [K][NC] fp32 -> WT [NC][K] bf16 (transposed: B-frag wants contiguous k per column)
__global__ void convw_kernel(const float* __restrict__ W, ushort* __restrict__ WT, int K, int NC) {
    int i = blockIdx.x * blockDim.x + threadIdx.x;
    if (i >= K * NC) return;
    int k = i / NC, n = i % NC;
    WT[n * K + k] = (ushort)bf16r(W[i]);
}

// ---------------- bf16 MFMA GEMM + fused attention dots ----------------
// H[N,NCT] = X[N,K] @ W[K,NCT] via mfma_f32_16x16x32_bf16.
// Block: 128 rows x 96 cols, 4 waves (wave w: rows w*32..+31, 2x6 16x16 C-frags).
template<int K, int NCT, int HEADS>
__global__ void gemm_mfma(const ushort* __restrict__ Xb, const ushort* __restrict__ WT,
                          const float* __restrict__ att_s, const float* __restrict__ att_d,
                          ushort* __restrict__ Hb, float* __restrict__ asrc,
                          float* __restrict__ adst, int N) {
    __shared__ ushort XT_l[128 * 40];
    __shared__ ushort WT_l[96 * 40];
    int tid = threadIdx.x;
    int wv = tid >> 6, lane = tid & 63;
    int m = lane & 15, quad = lane >> 4;
    int rb = blockIdx.x * 128;
    int c0 = blockIdx.y * 96;
    int mw = wv * 32;
    v4f acc[2][6];
#pragma unroll
    for (int mi = 0; mi < 2; mi++)
#pragma unroll
        for (int nb = 0; nb < 6; nb++) acc[mi][nb] = (v4f){0.f, 0.f, 0.f, 0.f};

    for (int k0 = 0; k0 < K; k0 += 32) {
#pragma unroll
        for (int t = 0; t < 2; t++) {
            int ch = tid + t * 256;
            int r = ch >> 2, kq = ch & 3;
            int rg = rb + r;
            uint4 v = make_uint4(0u, 0u, 0u, 0u);
            if (rg < N) v = *reinterpret_cast<const uint4*>(&Xb[(long)rg * K + k0 + kq * 8]);
            uint2* d = reinterpret_cast<uint2*>(&XT_l[r * 40 + kq * 8]);
            d[0] = make_uint2(v.x, v.y);
            d[1] = make_uint2(v.z, v.w);
        }
#pragma unroll
        for (int t = 0; t < 2; t++) {
            int ch = tid + t * 256;
            if (ch < 384) {
                int wr = ch >> 2, kq = ch & 3;
                uint4 v = *reinterpret_cast<const uint4*>(&WT[(long)(c0 + wr) * K + k0 + kq * 8]);
                uint2* d = reinterpret_cast<uint2*>(&WT_l[wr * 40 + kq * 8]);
                d[0] = make_uint2(v.x, v.y);
                d[1] = make_uint2(v.z, v.w);
            }
        }
        __syncthreads();
        v8s af[2], bf[6];
        af[0] = ld_frag(&XT_l[(mw + m) * 40 + quad * 8]);
        af[1] = ld_frag(&XT_l[(mw + 16 + m) * 40 + quad * 8]);
#pragma unroll
        for (int nb = 0; nb < 6; nb++)
            bf[nb] = ld_frag(&WT_l[(nb * 16 + m) * 40 + quad * 8]);
#pragma unroll
        for (int mi = 0; mi < 2; mi++)
#pragma unroll
            for (int nb = 0; nb < 6; nb++)
                acc[mi][nb] = __builtin_amdgcn_mfma_f32_16x16x32_bf16(af[mi], bf[nb], acc[mi][nb], 0, 0, 0);
        __syncthreads();
    }

#pragma unroll
    for (int mi = 0; mi < 2; mi++)
#pragma unroll
        for (int r = 0; r < 4; r++) {
            int R = rb + mw + mi * 16 + quad * 4 + r;
            if (R < N) {
#pragma unroll
                for (int nb = 0; nb < 6; nb++)
                    Hb[(long)R * NCT + c0 + nb * 16 + m] = (ushort)bf16r(acc[mi][nb][r]);
            }
        }

    // ---- fused attention dots from fp32 accumulator ----
    float aS[6], aD[6];
    int h0 = c0 / DD;
#pragma unroll
    for (int nb = 0; nb < 6; nb++) {
        int cb = nb * 16 + m;
        int hl = cb / DD;
        int cih = cb - hl * DD;
        aS[nb] = att_s[(h0 + hl) * DD + cih];
        aD[nb] = att_d[(h0 + hl) * DD + cih];
    }
#pragma unroll
    for (int mi = 0; mi < 2; mi++)
#pragma unroll
        for (int r = 0; r < 4; r++) {
            float ps0 = 0.f, ps1 = 0.f, pd0 = 0.f, pd1 = 0.f;
#pragma unroll
            for (int nb = 0; nb < 3; nb++) {
                ps0 = fmaf(acc[mi][nb][r], aS[nb], ps0);
                pd0 = fmaf(acc[mi][nb][r], aD[nb], pd0);
            }
#pragma unroll
            for (int nb = 3; nb < 6; nb++) {
                ps1 = fmaf(acc[mi][nb][r], aS[nb], ps1);
                pd1 = fmaf(acc[mi][nb][r], aD[nb], pd1);
            }
#pragma unroll
            for (int d = 1; d < 16; d <<= 1) {
                ps0 += __shfl_xor(ps0, d); ps1 += __shfl_xor(ps1, d);
                pd0 += __shfl_xor(pd0, d); pd1 += __shfl_xor(pd1, d);
            }
            int R = rb + mw + mi * 16 + quad * 4 + r;
            if (m == 0 && R < N) {
                asrc[R * HEADS + h0]     = ps0;
                asrc[R * HEADS + h0 + 1] = ps1;
                adst[R * HEADS + h0]     = pd0;
                adst[R * HEADS + h0 + 1] = pd1;
            }
        }
}

// ---------------- dst-centric fused softmax + aggregate + bias + relu ----------------
// R8: wlds padded to [HEADS][CAP+1] (per-head weight reads on distinct banks ->
// conflict-free); asrc loaded as float4/float2; pad-to-4 loop; float2 (v_pk_fma_f32)
// accumulation. bf16 H gather; OBF16 selects bf16 vs fp32 output.
template<int OUT, int HEADS, int PAIRS, bool OBF16>
__global__ void agg_kernel(const unsigned int* __restrict__ Hb,
                           const float* __restrict__ asrc, const float* __restrict__ adst,
                           const int* __restrict__ adj, const int* __restrict__ cnt,
                           const float* __restrict__ bias,
                           unsigned int* __restrict__ Ob, float* __restrict__ Of, int N) {
    typedef unsigned int pk_t __attribute__((ext_vector_type(PAIRS)));
    constexpr int NL = OUT / (2 * PAIRS);      // active gather lanes (48)
    __shared__ float wlds[4][HEADS][CAP + 1];  // +1: head stride 65 -> distinct banks
    __shared__ float dlds[4][HEADS];
    __shared__ int   slds[4][CAP];
    int wv = threadIdx.x >> 6;
    int lane = threadIdx.x & 63;
    int n = blockIdx.x * 4 + wv;
    bool valid = (n < N);
    int nn = valid ? n : 0;
    int deg_raw = cnt[nn];                     // issue cnt+adj concurrently
    int araw = adj[nn * CAP + lane];
    int deg = min(deg_raw, CAP);
    int s = (lane < deg) ? araw : 0;
    slds[wv][lane] = s;

    float av[HEADS];
    if constexpr (HEADS == 4) {
        float4 t = *reinterpret_cast<const float4*>(&asrc[s * 4]);
        av[0] = t.x; av[1] = t.y; av[2] = t.z; av[3] = t.w;
    } else {
        float2 t = *reinterpret_cast<const float2*>(&asrc[s * 2]);
        av[0] = t.x; av[1] = t.y;
    }
    float w[HEADS];
#pragma unroll
    for (int h = 0; h < HEADS; h++) {
        float e = av[h] + adst[nn * HEADS + h];
        e = (e < 0.f) ? 0.2f * e : e;               // leaky_relu, slope 0.2
        w[h] = (lane < deg) ? __expf(e) : 0.f;      // max-shift dropped: scale-invariant
        wlds[wv][h][lane] = w[h];
    }
#pragma unroll
    for (int h = 0; h < HEADS; h++) {               // den = wave-sum of weights
        float dsum = w[h];
#pragma unroll
        for (int off = 1; off < 64; off <<= 1) dsum += __shfl_xor(dsum, off);
        if (lane == 0) dlds[wv][h] = dsum;
    }
    __syncthreads();

    bool act = (lane < NL);
    int c = act ? lane * 2 * PAIRS : 0;
    int head = c / DD;
    const float* wrow = &wlds[wv][head][0];
    v2f acc2[PAIRS];
#pragma unroll
    for (int q = 0; q < PAIRS; q++) acc2[q] = (v2f){0.f, 0.f};

    for (int i = 0; i < deg; i += 4) {              // always full 4-wide batches
        int sv[4];
#pragma unroll
        for (int u = 0; u < 4; u++) sv[u] = slds[wv][i + u];
        pk_t hv[4];
#pragma unroll
        for (int u = 0; u < 4; u++)
            hv[u] = *reinterpret_cast<const pk_t*>(&Hb[((long)sv[u] * OUT + c) >> 1]);
#pragma unroll
        for (int u = 0; u < 4; u++) {
            float ww = wrow[i + u];
#pragma unroll
            for (int q = 0; q < PAIRS; q++) {
                v2f h2;
                h2.x = __uint_as_float(hv[u][q] << 16);
                h2.y = __uint_as_float(hv[u][q] & 0xFFFF0000u);
                acc2[q] += ww * h2;                 // v_pk_fma_f32
            }
        }
    }

    if (valid && act) {
        float invd = 1.f / (dlds[wv][head] + 1e-16f);
        if (OBF16) {
            pk_t pk;
#pragma unroll
            for (int q = 0; q < PAIRS; q++) {
                float o0 = fmaxf(fmaf(acc2[q].x, invd, bias[c + 2 * q]), 0.f);
                float o1 = fmaxf(fmaf(acc2[q].y, invd, bias[c + 2 * q + 1]), 0.f);
                pk[q] = bf16r(o0) | (bf16r(o1) << 16);
            }
            *reinterpret_cast<pk_t*>(&Ob[((long)n * OUT + c) >> 1]) = pk;
        } else {
#pragma unroll
            for (int q = 0; q < PAIRS; q++) {
                float o0 = fmaxf(fmaf(acc2[q].x, invd, bias[c + 2 * q]), 0.f);
                float o1 = fmaxf(fmaf(acc2[q].y, invd, bias[c + 2 * q + 1]), 0.f);
                *reinterpret_cast<float2*>(&Of[(long)n * OUT + c + 2 * q]) = make_float2(o0, o1);
            }
        }
    }
}

// ---------------- mean-pool: 128-thread groups, 64-node chunks, 4x-unrolled ----------------
__global__ void pool_kernel(const float* __restrict__ O, const int* __restrict__ batch,
                            float* __restrict__ sums, float* __restrict__ counts, int N) {
    int grp = threadIdx.x >> 7;                 // 4 groups of 128 per block
    int c = threadIdx.x & 127;                  // channel lane; active if < 96
    int n0 = (blockIdx.x * 4 + grp) * 64;
    if (n0 >= N) return;
    int nend = min(N, n0 + 64);
    bool act = (c < 96);
    float acc = 0.f; int cl = 0;
    int cur = batch[n0];
    int n = n0;
    for (; n + 4 <= nend; n += 4) {
        int g0 = batch[n], g1 = batch[n + 1], g2 = batch[n + 2], g3 = batch[n + 3];
        float v0 = 0.f, v1 = 0.f, v2 = 0.f, v3 = 0.f;
        if (act) {
            v0 = O[(long)n * 96 + c];       v1 = O[(long)(n + 1) * 96 + c];
            v2 = O[(long)(n + 2) * 96 + c]; v3 = O[(long)(n + 3) * 96 + c];
        }
#define POOL_STEP(g, v)                                                        \
        if ((g) != cur) {                                                      \
            if (act) atomicAdd(&sums[cur * 96 + c], acc);                      \
            if (c == 96) atomicAdd(&counts[cur], (float)cl);                   \
            acc = 0.f; cl = 0; cur = (g);                                      \
        }                                                                      \
        acc += (v); cl++;
        POOL_STEP(g0, v0) POOL_STEP(g1, v1) POOL_STEP(g2, v2) POOL_STEP(g3, v3)
    }
    for (; n < nend; n++) {
        int g = batch[n];
        float v = act ? O[(long)n * 96 + c] : 0.f;
        POOL_STEP(g, v)
    }
#undef POOL_STEP
    if (act) atomicAdd(&sums[cur * 96 + c], acc);
    if (c == 96) atomicAdd(&counts[cur], (float)cl);
}

// ---------------- FC head: one block per graph ----------------
__global__ void fc_kernel(const float* __restrict__ sums, const float* __restrict__ counts,
                          const float* __restrict__ W1, const float* __restrict__ b1,
                          const float* __restrict__ W2, const float* __restrict__ b2,
                          float* __restrict__ out) {
    __shared__ float p[96];
    __shared__ float h1[192];
    int g = blockIdx.x, tid = threadIdx.x;     // 192 threads
    if (tid < 96) p[tid] = sums[g * 96 + tid] / fmaxf(counts[g], 1.0f);
    __syncthreads();
    float s = b1[tid];
    for (int c = 0; c < 96; c++) s = fmaf(p[c], W1[c * 192 + tid], s);
    h1[tid] = fmaxf(s, 0.f);
    __syncthreads();
    if (tid < 96) {
        float s2 = b2[tid];
        for (int j = 0; j < 192; j++) s2 = fmaf(h1[j], W2[j * 96 + tid], s2);
        out[g * 96 + tid] = s2;
    }
}

extern "C" void kernel_launch(void* const* d_in, const int* in_sizes, int n_in,
                              void* d_out, int out_size, void* d_ws, size_t ws_size,
                              hipStream_t stream) {
    const float* x     = (const float*)d_in[0];
    const int*   ei    = (const int*)d_in[1];
    const int*   batch = (const int*)d_in[2];
    const float* W0  = (const float*)d_in[3];
    const float* as0 = (const float*)d_in[4];
    const float* ad0 = (const float*)d_in[5];
    const float* b0  = (const float*)d_in[6];
    const float* W1  = (const float*)d_in[7];
    const float* as1 = (const float*)d_in[8];
    const float* ad1 = (const float*)d_in[9];
    const float* b1  = (const float*)d_in[10];
    const float* W2  = (const float*)d_in[11];
    const float* as2 = (const float*)d_in[12];
    const float* ad2 = (const float*)d_in[13];
    const float* b2  = (const float*)d_in[14];
    const float* fcW1 = (const float*)d_in[15];
    const float* fcb1 = (const float*)d_in[16];
    const float* fcW2 = (const float*)d_in[17];
    const float* fcb2 = (const float*)d_in[18];

    const int N = in_sizes[0] / 128;
    const int E = in_sizes[1] / 2;

    char* ws = (char*)d_ws;
    unsigned int* Xb   = (unsigned int*)ws;                          // N*128 bf16 = N*256 B
    unsigned int* Hb   = (unsigned int*)(ws + (size_t)N * 256);      // N*192 bf16 = N*384 B
    unsigned int* Ob   = (unsigned int*)(ws + (size_t)N * 640);      // N*192 bf16 = N*384 B
    float*        Obuf = (float*)(ws + (size_t)N * 1024);            // N*96 f32  = N*384 B
    float*        ASRC = (float*)(ws + (size_t)N * 1408);            // N*4 f
    float*        ADST = (float*)(ws + (size_t)N * 1424);            // N*4 f
    int*          ADJ  = (int*)(ws + (size_t)N * 1440);              // N*CAP i  = N*256 B
    int*          CNT  = (int*)(ws + (size_t)N * 1696);              // N i
    float*        SUMS = (float*)(ws + (size_t)N * 1700);            // 64*96 f
    float*        COUNTS = SUMS + 64 * 96;                           // 64 f
    ushort*       WT0  = (ushort*)(COUNTS + 64);                     // 192*128 bf16
    ushort*       WT1  = WT0 + 192 * 128;                            // 96*192 bf16
    ushort*       WT2  = WT1 + 96 * 192;                             // 96*96 bf16

    hipMemsetAsync(CNT, 0, (size_t)N * 4 + (64 * 96 + 64) * 4, stream);

    int Et = E + N;
    build_adj_kernel<<<(Et + 255) / 256, 256, 0, stream>>>(ei, E, N, CNT, ADJ);

    long n2 = (long)N * 64;
    cast_x_kernel<<<(int)((n2 + 255) / 256), 256, 0, stream>>>(x, Xb, n2);
    convw_kernel<<<(128 * 192 + 255) / 256, 256, 0, stream>>>(W0, WT0, 128, 192);
    convw_kernel<<<(192 * 96 + 255) / 256, 256, 0, stream>>>(W1, WT1, 192, 96);
    convw_kernel<<<(96 * 96 + 255) / 256, 256, 0, stream>>>(W2, WT2, 96, 96);

    int gb = (N + 127) / 128;

    // layer 0: 128 -> 4x48
    gemm_mfma<128, 192, 4><<<dim3(gb, 2), 256, 0, stream>>>((const ushort*)Xb, WT0, as0, ad0,
                                                            (ushort*)Hb, ASRC, ADST, N);
    agg_kernel<192, 4, 2, true><<<(N + 3) / 4, 256, 0, stream>>>(Hb, ASRC, ADST, ADJ, CNT, b0, Ob, nullptr, N);

    // layer 1: 192 -> 2x48
    gemm_mfma<192, 96, 2><<<dim3(gb, 1), 256, 0, stream>>>((const ushort*)Ob, WT1, as1, ad1,
                                                           (ushort*)Hb, ASRC, ADST, N);
    agg_kernel<96, 2, 1, true><<<(N + 3) / 4, 256, 0, stream>>>(Hb, ASRC, ADST, ADJ, CNT, b1, Ob, nullptr, N);

    // layer 2: 96 -> 2x48
    gemm_mfma<96, 96, 2><<<dim3(gb, 1), 256, 0, stream>>>((const ushort*)Ob, WT2, as2, ad2,
                                                          (ushort*)Hb, ASRC, ADST, N);
    agg_kernel<96, 2, 1, false><<<(N + 3) / 4, 256, 0, stream>>>(Hb, ASRC, ADST, ADJ, CNT, b2, nullptr, Obuf, N);

    // pooling + FC head
    pool_kernel<<<(N / 256) + 1, 512, 0, stream>>>(Obuf, batch, SUMS, COUNTS, N);
    fc_kernel<<<64, 192, 0, stream>>>(SUMS, COUNTS, fcW1, fcb1, fcW2, fcb2, (float*)d_out);
}